// Round 2
// baseline (3302.677 us; speedup 1.0000x reference)
//
#include <hip/hip_runtime.h>

#define TT 512
#define BB 256
#define II 128
#define HH 256
#define LDH 264  // shorts/LDS row: 512B data + 16B pad (keeps 16B row alignment)

typedef __attribute__((ext_vector_type(8))) short short8;
typedef __attribute__((ext_vector_type(4))) float floatx4;
typedef __attribute__((ext_vector_type(4))) float fvec4;
typedef unsigned long long u64;

// ws layout (shorts): bf16 weights, h1g[2][B][H], h2g[2][B][H], then flags.
#define OFF_WIH0 0
#define OFF_WHH0 (OFF_WIH0 + 3 * HH * II)
#define OFF_WIH1 (OFF_WHH0 + 3 * HH * HH)
#define OFF_WHH1 (OFF_WIH1 + 3 * HH * HH)
#define W_TOTAL (OFF_WHH1 + 3 * HH * HH)
#define H1G_OFF W_TOTAL
#define H2G_OFF (H1G_OFF + 2 * BB * HH)
#define WS_SHORTS (H2G_OFF + 2 * BB * HH)
#define FLAGS_OFF_BYTES (WS_SHORTS * 2)
#define FLAG_STRIDE 32  // uints; 128B spacing kills false sharing

__device__ __forceinline__ short f2bf(float f) {
  unsigned u = __builtin_bit_cast(unsigned, f);
  u = u + 0x7fffu + ((u >> 16) & 1u);
  return (short)(u >> 16);
}
__device__ __forceinline__ float fast_sigmoid(float x) {
  return __fdividef(1.0f, 1.0f + __expf(-x));
}
__device__ __forceinline__ float fast_tanh(float x) {
  return 1.0f - __fdividef(2.0f, 1.0f + __expf(2.0f * x));
}
__device__ __forceinline__ short8 cvt8(const float* __restrict__ p) {
  fvec4 lo = *(const fvec4*)p;
  fvec4 hi = *(const fvec4*)(p + 4);
  short8 r;
  r[0] = f2bf(lo[0]); r[1] = f2bf(lo[1]); r[2] = f2bf(lo[2]); r[3] = f2bf(lo[3]);
  r[4] = f2bf(hi[0]); r[5] = f2bf(hi[1]); r[6] = f2bf(hi[2]); r[7] = f2bf(hi[3]);
  return r;
}
__device__ __forceinline__ u64 ld_sc1(const u64* p) {
  return __hip_atomic_load(p, __ATOMIC_RELAXED, __HIP_MEMORY_SCOPE_AGENT);
}

__global__ __launch_bounds__(256) void cvt_weights(
    const float* __restrict__ w0, const float* __restrict__ w1,
    const float* __restrict__ w2, const float* __restrict__ w3,
    short* __restrict__ out) {
  int i = blockIdx.x * 256 + threadIdx.x;
  if (i >= W_TOTAL) return;
  float v;
  if (i < OFF_WHH0)      v = w0[i - OFF_WIH0];
  else if (i < OFF_WIH1) v = w1[i - OFF_WHH0];
  else if (i < OFF_WHH1) v = w2[i - OFF_WIH1];
  else                   v = w3[i - OFF_WHH1];
  out[i] = f2bf(v);
}

__global__ __launch_bounds__(256) void init_state(unsigned* __restrict__ hz,
                                                  unsigned* __restrict__ flags) {
  int i = blockIdx.x * 256 + threadIdx.x;
  if (i < 2 * BB * HH) hz[i] = 0u;  // h1g+h2g = 4*B*H shorts = 2*B*H uints
  if (i < 16 * FLAG_STRIDE) flags[i] = 0u;
}

// 128 blocks = (pair q 0..7) x (ht 0..15), 384 thr = 6 waves.
// Each block serves TWO batch tiles (btA=q, btB=q+8) with the SAME weight
// VGPRs (weights depend on ht/gate/layer only). One sync round (poll + stage
// + publish-drain + flag add) covers TWO recurrence steps -> exposed exchange
// latency per step halves. Sync topology identical to the proven 16-block
// per-counter protocol (same 16 peer blocks, one counter per pair).
__global__ __launch_bounds__(384) void gru_sync(
    const float* __restrict__ x, const short* __restrict__ wb,
    const float* __restrict__ bih0, const float* __restrict__ bhh0,
    const float* __restrict__ bih1, const float* __restrict__ bhh1,
    const float* __restrict__ Wfc, const float* __restrict__ bfc,
    short* __restrict__ h1g, short* __restrict__ h2g,
    unsigned* __restrict__ flags, float* __restrict__ out) {
  const int tid = threadIdx.x;
  const int lane = tid & 63;
  const int w = tid >> 6;
  const int quad = lane >> 4;
  const int col = lane & 15;
  const int q = blockIdx.x & 7;   // pair id: btA=q, btB=q+8
  const int ht = blockIdx.x >> 3;
  const int layer = w / 3, gate = w % 3;
  const int j = ht * 16 + col;

  // [grp][0]=h1[p-1], [grp][1]=h2[p-2]
  __shared__ __align__(16) short lds[2][2][16][LDH];
  // [grp][0]=IH acc, [grp][1]=HH acc
  __shared__ __align__(16) float gt[2][2][6][16][20];

  // ---- weights -> VGPRs (wave-uniform role; shared by both groups) ----
  const short* wih = wb + (layer ? OFF_WIH1 : OFF_WIH0);
  const short* whh = wb + (layer ? OFF_WHH1 : OFF_WHH0);
  short8 wfI[8], wfH[8];
  if (layer == 0) {
#pragma unroll
    for (int f = 0; f < 4; ++f)
      wfI[f] = *(const short8*)(wih + (gate * HH + j) * II + f * 32 + quad * 8);
#pragma unroll
    for (int f = 4; f < 8; ++f) wfI[f] = short8{0, 0, 0, 0, 0, 0, 0, 0};
  } else {
#pragma unroll
    for (int f = 0; f < 8; ++f)
      wfI[f] = *(const short8*)(wih + (gate * HH + j) * HH + f * 32 + quad * 8);
  }
#pragma unroll
  for (int f = 0; f < 8; ++f)
    wfH[f] = *(const short8*)(whh + (gate * HH + j) * HH + f * 32 + quad * 8);

  const float* bihL = layer ? bih1 : bih0;
  const float* bhhL = layer ? bhh1 : bhh0;
  float bI, bH;
  if (gate == 2) { bI = bihL[2 * HH + j]; bH = bhhL[2 * HH + j]; }
  else { bI = bihL[gate * HH + j] + bhhL[gate * HH + j]; bH = 0.f; }

  // ---- elementwise roles: 2 adjacent cols per thread, both groups ----
  float h1aA = 0.f, h1bA = 0.f, h2aA = 0.f, h2bA = 0.f;
  float h1aB = 0.f, h1bB = 0.f, h2aB = 0.f, h2bB = 0.f;
  const int r1 = tid >> 3, c1 = (tid & 7) * 2;                  // tid < 128
  const int r2 = (tid - 256) >> 3, c2 = ((tid - 256) & 7) * 2;  // tid >= 256

  unsigned* cnt = flags + q * FLAG_STRIDE;
  const size_t tbaseA = (size_t)(q * 16) * HH;
  const size_t tbaseB = (size_t)((q + 8) * 16) * HH;

  for (int p = 0; p <= TT; ++p) {
    // x prefetch for both groups (independent of peers; L2-cached loads)
    short8 axA[4], axB[4];
    if (w < 3 && p < TT) {
      const float* xrA = x + ((size_t)p * BB + q * 16 + col) * II + quad * 8;
      const float* xrB = xrA + (size_t)8 * 16 * II;
#pragma unroll
      for (int f = 0; f < 4; ++f) {
        axA[f] = cvt8(xrA + f * 32);
        axB[f] = cvt8(xrB + f * 32);
      }
    }

    if (p > 0) {
      if (tid == 0) {
        unsigned tgt = 16u * (unsigned)p;
        int guard = 0;
        while (__hip_atomic_load(cnt, __ATOMIC_RELAXED,
                                 __HIP_MEMORY_SCOPE_AGENT) < tgt &&
               guard < (1 << 20))
          ++guard;
      }
      __syncthreads();
    }

    // ---- stage peer tiles -> LDS via sc1 u64 loads (4 x 8KB) ----
    {
      const u64* s1A = (const u64*)(h1g + ((p + 1) & 1) * BB * HH + tbaseA);
      const u64* s2A = (const u64*)(h2g + (p & 1) * BB * HH + tbaseA);
      const u64* s1B = (const u64*)(h1g + ((p + 1) & 1) * BB * HH + tbaseB);
      const u64* s2B = (const u64*)(h2g + (p & 1) * BB * HH + tbaseB);
      u64* d1A = (u64*)&lds[0][0][0][0];
      u64* d2A = (u64*)&lds[0][1][0][0];
      u64* d1B = (u64*)&lds[1][0][0][0];
      u64* d2B = (u64*)&lds[1][1][0][0];
      if (tid < 256) {
#pragma unroll
        for (int qq = 0; qq < 4; ++qq) {
          int i = tid * 4 + qq, row = i >> 6, c = i & 63;
          d1A[row * (LDH / 4) + c] = ld_sc1(s1A + i);
          d1B[row * (LDH / 4) + c] = ld_sc1(s1B + i);
        }
      }
      if (tid >= 128) {
        int t2 = tid - 128;
#pragma unroll
        for (int qq = 0; qq < 4; ++qq) {
          int i = t2 * 4 + qq, row = i >> 6, c = i & 63;
          d2A[row * (LDH / 4) + c] = ld_sc1(s2A + i);
          d2B[row * (LDH / 4) + c] = ld_sc1(s2B + i);
        }
      }
    }
    __syncthreads();

    // ---- MFMA both groups (weights in regs, A frags from LDS) ----
    floatx4 aIA = floatx4{bI, bI, bI, bI};
    floatx4 aHA = floatx4{bH, bH, bH, bH};
    floatx4 aIB = floatx4{bI, bI, bI, bI};
    floatx4 aHB = floatx4{bH, bH, bH, bH};
    const short* a1A = &lds[0][0][col][0];
    const short* a2A = &lds[0][1][col][0];
    const short* a1B = &lds[1][0][col][0];
    const short* a2B = &lds[1][1][col][0];
    if (layer == 0) {
      if (p < TT) {
#pragma unroll
        for (int f = 0; f < 4; ++f) {
          aIA = __builtin_amdgcn_mfma_f32_16x16x32_bf16(axA[f], wfI[f], aIA, 0, 0, 0);
          aIB = __builtin_amdgcn_mfma_f32_16x16x32_bf16(axB[f], wfI[f], aIB, 0, 0, 0);
        }
      }
#pragma unroll
      for (int f = 0; f < 8; ++f) {
        short8 aA = *(const short8*)(a1A + f * 32 + quad * 8);
        short8 aB = *(const short8*)(a1B + f * 32 + quad * 8);
        aHA = __builtin_amdgcn_mfma_f32_16x16x32_bf16(aA, wfH[f], aHA, 0, 0, 0);
        aHB = __builtin_amdgcn_mfma_f32_16x16x32_bf16(aB, wfH[f], aHB, 0, 0, 0);
      }
    } else {
#pragma unroll
      for (int f = 0; f < 8; ++f) {
        short8 aA = *(const short8*)(a1A + f * 32 + quad * 8);
        short8 aB = *(const short8*)(a1B + f * 32 + quad * 8);
        aIA = __builtin_amdgcn_mfma_f32_16x16x32_bf16(aA, wfI[f], aIA, 0, 0, 0);
        aIB = __builtin_amdgcn_mfma_f32_16x16x32_bf16(aB, wfI[f], aIB, 0, 0, 0);
      }
#pragma unroll
      for (int f = 0; f < 8; ++f) {
        short8 aA = *(const short8*)(a2A + f * 32 + quad * 8);
        short8 aB = *(const short8*)(a2B + f * 32 + quad * 8);
        aHA = __builtin_amdgcn_mfma_f32_16x16x32_bf16(aA, wfH[f], aHA, 0, 0, 0);
        aHB = __builtin_amdgcn_mfma_f32_16x16x32_bf16(aB, wfH[f], aHB, 0, 0, 0);
      }
    }
#pragma unroll
    for (int i = 0; i < 4; ++i) {
      gt[0][0][w][quad * 4 + i][col] = aIA[i];
      gt[0][1][w][quad * 4 + i][col] = aHA[i];
      gt[1][0][w][quad * 4 + i][col] = aIB[i];
      gt[1][1][w][quad * 4 + i][col] = aHB[i];
    }
    __syncthreads();

    // ---- elementwise + publish (sc1 u32 stores), both groups ----
    if (tid < 128 && p < TT) {
      {  // group A h1
        float rA = fast_sigmoid(gt[0][0][0][r1][c1] + gt[0][1][0][r1][c1]);
        float zA = fast_sigmoid(gt[0][0][1][r1][c1] + gt[0][1][1][r1][c1]);
        float nA = fast_tanh(gt[0][0][2][r1][c1] + rA * gt[0][1][2][r1][c1]);
        h1aA = nA + zA * (h1aA - nA);
        float rB = fast_sigmoid(gt[0][0][0][r1][c1 + 1] + gt[0][1][0][r1][c1 + 1]);
        float zB = fast_sigmoid(gt[0][0][1][r1][c1 + 1] + gt[0][1][1][r1][c1 + 1]);
        float nB = fast_tanh(gt[0][0][2][r1][c1 + 1] + rB * gt[0][1][2][r1][c1 + 1]);
        h1bA = nB + zB * (h1bA - nB);
        unsigned val = ((unsigned)(unsigned short)f2bf(h1bA) << 16) |
                       (unsigned)(unsigned short)f2bf(h1aA);
        unsigned* dst = (unsigned*)(h1g + (p & 1) * BB * HH +
                                    (q * 16 + r1) * HH + ht * 16 + c1);
        __hip_atomic_store(dst, val, __ATOMIC_RELAXED, __HIP_MEMORY_SCOPE_AGENT);
      }
      {  // group B h1
        float rA = fast_sigmoid(gt[1][0][0][r1][c1] + gt[1][1][0][r1][c1]);
        float zA = fast_sigmoid(gt[1][0][1][r1][c1] + gt[1][1][1][r1][c1]);
        float nA = fast_tanh(gt[1][0][2][r1][c1] + rA * gt[1][1][2][r1][c1]);
        h1aB = nA + zA * (h1aB - nA);
        float rB = fast_sigmoid(gt[1][0][0][r1][c1 + 1] + gt[1][1][0][r1][c1 + 1]);
        float zB = fast_sigmoid(gt[1][0][1][r1][c1 + 1] + gt[1][1][1][r1][c1 + 1]);
        float nB = fast_tanh(gt[1][0][2][r1][c1 + 1] + rB * gt[1][1][2][r1][c1 + 1]);
        h1bB = nB + zB * (h1bB - nB);
        unsigned val = ((unsigned)(unsigned short)f2bf(h1bB) << 16) |
                       (unsigned)(unsigned short)f2bf(h1aB);
        unsigned* dst = (unsigned*)(h1g + (p & 1) * BB * HH +
                                    ((q + 8) * 16 + r1) * HH + ht * 16 + c1);
        __hip_atomic_store(dst, val, __ATOMIC_RELAXED, __HIP_MEMORY_SCOPE_AGENT);
      }
    }
    if (tid >= 256 && p > 0) {
      {  // group A h2
        float rA = fast_sigmoid(gt[0][0][3][r2][c2] + gt[0][1][3][r2][c2]);
        float zA = fast_sigmoid(gt[0][0][4][r2][c2] + gt[0][1][4][r2][c2]);
        float nA = fast_tanh(gt[0][0][5][r2][c2] + rA * gt[0][1][5][r2][c2]);
        h2aA = nA + zA * (h2aA - nA);
        float rB = fast_sigmoid(gt[0][0][3][r2][c2 + 1] + gt[0][1][3][r2][c2 + 1]);
        float zB = fast_sigmoid(gt[0][0][4][r2][c2 + 1] + gt[0][1][4][r2][c2 + 1]);
        float nB = fast_tanh(gt[0][0][5][r2][c2 + 1] + rB * gt[0][1][5][r2][c2 + 1]);
        h2bA = nB + zB * (h2bA - nB);
        unsigned val = ((unsigned)(unsigned short)f2bf(h2bA) << 16) |
                       (unsigned)(unsigned short)f2bf(h2aA);
        unsigned* dst = (unsigned*)(h2g + ((p + 1) & 1) * BB * HH +
                                    (q * 16 + r2) * HH + ht * 16 + c2);
        __hip_atomic_store(dst, val, __ATOMIC_RELAXED, __HIP_MEMORY_SCOPE_AGENT);
      }
      {  // group B h2
        float rA = fast_sigmoid(gt[1][0][3][r2][c2] + gt[1][1][3][r2][c2]);
        float zA = fast_sigmoid(gt[1][0][4][r2][c2] + gt[1][1][4][r2][c2]);
        float nA = fast_tanh(gt[1][0][5][r2][c2] + rA * gt[1][1][5][r2][c2]);
        h2aB = nA + zA * (h2aB - nA);
        float rB = fast_sigmoid(gt[1][0][3][r2][c2 + 1] + gt[1][1][3][r2][c2 + 1]);
        float zB = fast_sigmoid(gt[1][0][4][r2][c2 + 1] + gt[1][1][4][r2][c2 + 1]);
        float nB = fast_tanh(gt[1][0][5][r2][c2 + 1] + rB * gt[1][1][5][r2][c2 + 1]);
        h2bB = nB + zB * (h2bB - nB);
        unsigned val = ((unsigned)(unsigned short)f2bf(h2bB) << 16) |
                       (unsigned)(unsigned short)f2bf(h2aB);
        unsigned* dst = (unsigned*)(h2g + ((p + 1) & 1) * BB * HH +
                                    ((q + 8) * 16 + r2) * HH + ht * 16 + c2);
        __hip_atomic_store(dst, val, __ATOMIC_RELAXED, __HIP_MEMORY_SCOPE_AGENT);
      }
    }
    __syncthreads();  // vmcnt(0) drain: all sc1 publishes globally visible
    if (tid == 0)
      __hip_atomic_fetch_add(cnt, 1u, __ATOMIC_RELAXED,
                             __HIP_MEMORY_SCOPE_AGENT);
  }

  // ---- FC epilogue: out = h2[511] @ Wfc^T + bfc, both groups ----
  if (tid == 0) {
    unsigned tgt = 16u * (unsigned)(TT + 1);
    int guard = 0;
    while (__hip_atomic_load(cnt, __ATOMIC_RELAXED, __HIP_MEMORY_SCOPE_AGENT) <
               tgt &&
           guard < (1 << 20))
      ++guard;
  }
  __syncthreads();
  {
    const u64* sA = (const u64*)(h2g + 1 * BB * HH + tbaseA);  // parity (TT+1)&1=1
    const u64* sB = (const u64*)(h2g + 1 * BB * HH + tbaseB);
    u64* dA = (u64*)&lds[0][0][0][0];
    u64* dB = (u64*)&lds[1][0][0][0];
    if (tid < 256) {
#pragma unroll
      for (int qq = 0; qq < 4; ++qq) {
        int i = tid * 4 + qq, row = i >> 6, c = i & 63;
        dA[row * (LDH / 4) + c] = ld_sc1(sA + i);
        dB[row * (LDH / 4) + c] = ld_sc1(sB + i);
      }
    }
  }
  __syncthreads();
  if (w < 2) {
    const int g = w;  // wave0 -> group A, wave1 -> group B
    const short* av = &lds[g][0][col][0];
    float bbv = bfc[j];
    floatx4 acc = floatx4{bbv, bbv, bbv, bbv};
#pragma unroll
    for (int f = 0; f < 8; ++f) {
      short8 a = *(const short8*)(av + f * 32 + quad * 8);
      short8 bfrag = cvt8(Wfc + j * HH + f * 32 + quad * 8);
      acc = __builtin_amdgcn_mfma_f32_16x16x32_bf16(a, bfrag, acc, 0, 0, 0);
    }
    const int brow = (g ? (q + 8) : q) * 16;
#pragma unroll
    for (int i = 0; i < 4; ++i)
      out[(size_t)(brow + quad * 4 + i) * HH + j] = acc[i];
  }
}

extern "C" void kernel_launch(void* const* d_in, const int* in_sizes, int n_in,
                              void* d_out, int out_size, void* d_ws,
                              size_t ws_size, hipStream_t stream) {
  const float* x = (const float*)d_in[0];
  const float* Wih0 = (const float*)d_in[1];
  const float* Whh0 = (const float*)d_in[2];
  const float* bih0 = (const float*)d_in[3];
  const float* bhh0 = (const float*)d_in[4];
  const float* Wih1 = (const float*)d_in[5];
  const float* Whh1 = (const float*)d_in[6];
  const float* bih1 = (const float*)d_in[7];
  const float* bhh1 = (const float*)d_in[8];
  const float* Wfc = (const float*)d_in[9];
  const float* bfc = (const float*)d_in[10];

  short* wb = (short*)d_ws;
  short* h1g = wb + H1G_OFF;
  short* h2g = wb + H2G_OFF;
  unsigned* flags = (unsigned*)((char*)d_ws + FLAGS_OFF_BYTES);
  unsigned* hz = (unsigned*)(wb + H1G_OFF);

  cvt_weights<<<(W_TOTAL + 255) / 256, 256, 0, stream>>>(Wih0, Whh0, Wih1, Whh1, wb);
  init_state<<<(2 * BB * HH + 255) / 256, 256, 0, stream>>>(hz, flags);
  gru_sync<<<128, 384, 0, stream>>>(x, wb, bih0, bhh0, bih1, bhh1, Wfc, bfc,
                                    h1g, h2g, flags, (float*)d_out);
}

// Round 3
// 1757.871 us; speedup vs baseline: 1.8788x; 1.8788x over previous
//
#include <hip/hip_runtime.h>

#define TT 512
#define BB 256
#define II 128
#define HH 256
#define LDH 264  // shorts/LDS row: 512B data + 16B pad (keeps 16B row alignment)

typedef __attribute__((ext_vector_type(8))) short short8;
typedef __attribute__((ext_vector_type(4))) float floatx4;
typedef __attribute__((ext_vector_type(4))) float fvec4;
typedef unsigned long long u64;

// ws layout (shorts): bf16 weights, h1g[2][B][H], h2g[2][B][H], then flags.
#define OFF_WIH0 0
#define OFF_WHH0 (OFF_WIH0 + 3 * HH * II)
#define OFF_WIH1 (OFF_WHH0 + 3 * HH * HH)
#define OFF_WHH1 (OFF_WIH1 + 3 * HH * HH)
#define W_TOTAL (OFF_WHH1 + 3 * HH * HH)
#define H1G_OFF W_TOTAL
#define H2G_OFF (H1G_OFF + 2 * BB * HH)
#define WS_SHORTS (H2G_OFF + 2 * BB * HH)
#define FLAGS_OFF_BYTES (WS_SHORTS * 2)
#define FLAG_STRIDE 32  // uints per bt-group; 16 flags live in one 64B line

__device__ __forceinline__ short f2bf(float f) {
  unsigned u = __builtin_bit_cast(unsigned, f);
  u = u + 0x7fffu + ((u >> 16) & 1u);
  return (short)(u >> 16);
}
__device__ __forceinline__ float fast_sigmoid(float x) {
  return __fdividef(1.0f, 1.0f + __expf(-x));
}
__device__ __forceinline__ float fast_tanh(float x) {
  return 1.0f - __fdividef(2.0f, 1.0f + __expf(2.0f * x));
}
__device__ __forceinline__ short8 cvt8(const float* __restrict__ p) {
  fvec4 lo = *(const fvec4*)p;
  fvec4 hi = *(const fvec4*)(p + 4);
  short8 r;
  r[0] = f2bf(lo[0]); r[1] = f2bf(lo[1]); r[2] = f2bf(lo[2]); r[3] = f2bf(lo[3]);
  r[4] = f2bf(hi[0]); r[5] = f2bf(hi[1]); r[6] = f2bf(hi[2]); r[7] = f2bf(hi[3]);
  return r;
}
__device__ __forceinline__ u64 ld_sc1(const u64* p) {
  return __hip_atomic_load(p, __ATOMIC_RELAXED, __HIP_MEMORY_SCOPE_AGENT);
}
__device__ __forceinline__ unsigned ld_flag(const unsigned* p) {
  return __hip_atomic_load(p, __ATOMIC_RELAXED, __HIP_MEMORY_SCOPE_AGENT);
}
__device__ __forceinline__ void st_flag(unsigned* p, unsigned v) {
  __hip_atomic_store(p, v, __ATOMIC_RELAXED, __HIP_MEMORY_SCOPE_AGENT);
}

__global__ __launch_bounds__(256) void cvt_weights(
    const float* __restrict__ w0, const float* __restrict__ w1,
    const float* __restrict__ w2, const float* __restrict__ w3,
    short* __restrict__ out) {
  int i = blockIdx.x * 256 + threadIdx.x;
  if (i >= W_TOTAL) return;
  float v;
  if (i < OFF_WHH0)      v = w0[i - OFF_WIH0];
  else if (i < OFF_WIH1) v = w1[i - OFF_WHH0];
  else if (i < OFF_WHH1) v = w2[i - OFF_WIH1];
  else                   v = w3[i - OFF_WHH1];
  out[i] = f2bf(v);
}

__global__ __launch_bounds__(256) void init_state(unsigned* __restrict__ hz,
                                                  unsigned* __restrict__ flags) {
  int i = blockIdx.x * 256 + threadIdx.x;
  if (i < 2 * BB * HH) hz[i] = 0u;  // h1g+h2g = 4*B*H shorts = 2*B*H uints
  if (i < 16 * FLAG_STRIDE) flags[i] = 0u;
}

// 256 blocks = (bt 0..15) x (ht 0..15), 384 thr = 6 waves.
// Wave w: layer=w/3, gate=w%3; owns output cols [ht*16,ht*16+16); its weight
// B-fragments live in VGPRs for the whole kernel. Phase p computes h1[p] and
// h2[p-1]. Cross-block h exchange via sc1 (L2-bypassing) relaxed agent atomics.
// Sync: per-(bt,ht) flag slots (16 per group in one 64B line) written by
// independent STORES (no RMW serialization); 16-lane wave-0 poll with ballot.
// Staging: all sc1 loads -> regs, one wait, then all ds_writes (no per-pair
// load->write round trips).
__global__ __launch_bounds__(384) void gru_sync(
    const float* __restrict__ x, const short* __restrict__ wb,
    const float* __restrict__ bih0, const float* __restrict__ bhh0,
    const float* __restrict__ bih1, const float* __restrict__ bhh1,
    const float* __restrict__ Wfc, const float* __restrict__ bfc,
    short* __restrict__ h1g, short* __restrict__ h2g,
    unsigned* __restrict__ flags, float* __restrict__ out) {
  const int tid = threadIdx.x;
  const int lane = tid & 63;
  const int w = tid >> 6;
  const int quad = lane >> 4;
  const int col = lane & 15;
  const int bt = blockIdx.x & 15;
  const int ht = blockIdx.x >> 4;
  const int layer = w / 3, gate = w % 3;
  const int j = ht * 16 + col;

  __shared__ __align__(16) short ldsA[2][16][LDH];  // [0]=h1[p-1], [1]=h2[p-2]
  __shared__ __align__(16) float gt[2][6][16][20];  // [0]=IH acc, [1]=HH acc

  // ---- weights -> VGPRs (wave-uniform role) ----
  const short* wih = wb + (layer ? OFF_WIH1 : OFF_WIH0);
  const short* whh = wb + (layer ? OFF_WHH1 : OFF_WHH0);
  short8 wfI[8], wfH[8];
  if (layer == 0) {
#pragma unroll
    for (int f = 0; f < 4; ++f)
      wfI[f] = *(const short8*)(wih + (gate * HH + j) * II + f * 32 + quad * 8);
#pragma unroll
    for (int f = 4; f < 8; ++f) wfI[f] = short8{0, 0, 0, 0, 0, 0, 0, 0};
  } else {
#pragma unroll
    for (int f = 0; f < 8; ++f)
      wfI[f] = *(const short8*)(wih + (gate * HH + j) * HH + f * 32 + quad * 8);
  }
#pragma unroll
  for (int f = 0; f < 8; ++f)
    wfH[f] = *(const short8*)(whh + (gate * HH + j) * HH + f * 32 + quad * 8);

  const float* bihL = layer ? bih1 : bih0;
  const float* bhhL = layer ? bhh1 : bhh0;
  float bI, bH;
  if (gate == 2) { bI = bihL[2 * HH + j]; bH = bhhL[2 * HH + j]; }
  else { bI = bihL[gate * HH + j] + bhhL[gate * HH + j]; bH = 0.f; }

  // ---- elementwise roles: 2 adjacent cols per thread, stable over phases ----
  float h1a = 0.f, h1b = 0.f, h2a = 0.f, h2b = 0.f;
  const int r1 = tid >> 3, c1 = (tid & 7) * 2;              // tid < 128
  const int r2 = (tid - 256) >> 3, c2 = ((tid - 256) & 7) * 2;  // tid >= 256

  unsigned* fl = flags + bt * FLAG_STRIDE;  // 16 slots, one 64B line
  const size_t tbase = (size_t)(bt * 16) * HH;  // batch-tile base (shorts)

  for (int p = 0; p <= TT; ++p) {
    // x prefetch (independent of peers; L2-cached normal loads)
    short8 ax[4];
    if (w < 3 && p < TT) {
      const float* xr = x + ((size_t)p * BB + bt * 16 + col) * II + quad * 8;
#pragma unroll
      for (int f = 0; f < 4; ++f) ax[f] = cvt8(xr + f * 32);
    }

    if (p > 0) {
      if (tid < 64) {  // wave 0: 16-lane parallel flag poll, one load/round
        const unsigned tgt = (unsigned)p;
        int guard = 0;
        for (;;) {
          unsigned v = tgt;
          if (lane < 16) v = ld_flag(fl + lane);
          if (__all(v >= tgt) || ++guard > (1 << 20)) break;
        }
      }
      __syncthreads();
    }

    // ---- stage peer tiles: all sc1 loads -> regs, then all LDS writes ----
    {
      const u64* s1 = (const u64*)(h1g + ((p + 1) & 1) * BB * HH + tbase);
      const u64* s2 = (const u64*)(h2g + (p & 1) * BB * HH + tbase);
      u64 t1[4], t2[4];
      if (tid < 256) {
#pragma unroll
        for (int qq = 0; qq < 4; ++qq) t1[qq] = ld_sc1(s1 + tid * 4 + qq);
      }
      if (tid >= 128) {
        const int ti = tid - 128;
#pragma unroll
        for (int qq = 0; qq < 4; ++qq) t2[qq] = ld_sc1(s2 + ti * 4 + qq);
      }
      u64* d1 = (u64*)&ldsA[0][0][0];
      u64* d2 = (u64*)&ldsA[1][0][0];
      if (tid < 256) {
#pragma unroll
        for (int qq = 0; qq < 4; ++qq) {
          int i = tid * 4 + qq, row = i >> 6, c = i & 63;
          d1[row * (LDH / 4) + c] = t1[qq];
        }
      }
      if (tid >= 128) {
        const int ti = tid - 128;
#pragma unroll
        for (int qq = 0; qq < 4; ++qq) {
          int i = ti * 4 + qq, row = i >> 6, c = i & 63;
          d2[row * (LDH / 4) + c] = t2[qq];
        }
      }
    }
    __syncthreads();

    // ---- MFMA (weights in regs, A frags from LDS) ----
    floatx4 aI = floatx4{bI, bI, bI, bI};
    floatx4 aH = floatx4{bH, bH, bH, bH};
    const short* a1 = &ldsA[0][col][0];
    const short* a2 = &ldsA[1][col][0];
    if (layer == 0) {
      if (p < TT) {
#pragma unroll
        for (int f = 0; f < 4; ++f)
          aI = __builtin_amdgcn_mfma_f32_16x16x32_bf16(ax[f], wfI[f], aI, 0, 0, 0);
      }
#pragma unroll
      for (int f = 0; f < 8; ++f) {
        short8 a = *(const short8*)(a1 + f * 32 + quad * 8);
        aH = __builtin_amdgcn_mfma_f32_16x16x32_bf16(a, wfH[f], aH, 0, 0, 0);
      }
    } else {
#pragma unroll
      for (int f = 0; f < 8; ++f) {
        short8 a = *(const short8*)(a1 + f * 32 + quad * 8);
        aI = __builtin_amdgcn_mfma_f32_16x16x32_bf16(a, wfI[f], aI, 0, 0, 0);
      }
#pragma unroll
      for (int f = 0; f < 8; ++f) {
        short8 a = *(const short8*)(a2 + f * 32 + quad * 8);
        aH = __builtin_amdgcn_mfma_f32_16x16x32_bf16(a, wfH[f], aH, 0, 0, 0);
      }
    }
#pragma unroll
    for (int i = 0; i < 4; ++i) {
      gt[0][w][quad * 4 + i][col] = aI[i];
      gt[1][w][quad * 4 + i][col] = aH[i];
    }
    __syncthreads();

    // ---- elementwise + publish (sc1 u32 stores, no dirty L2 lines) ----
    if (tid < 128 && p < TT) {
      float rA = fast_sigmoid(gt[0][0][r1][c1] + gt[1][0][r1][c1]);
      float zA = fast_sigmoid(gt[0][1][r1][c1] + gt[1][1][r1][c1]);
      float nA = fast_tanh(gt[0][2][r1][c1] + rA * gt[1][2][r1][c1]);
      h1a = nA + zA * (h1a - nA);
      float rB = fast_sigmoid(gt[0][0][r1][c1 + 1] + gt[1][0][r1][c1 + 1]);
      float zB = fast_sigmoid(gt[0][1][r1][c1 + 1] + gt[1][1][r1][c1 + 1]);
      float nB = fast_tanh(gt[0][2][r1][c1 + 1] + rB * gt[1][2][r1][c1 + 1]);
      h1b = nB + zB * (h1b - nB);
      unsigned val = ((unsigned)(unsigned short)f2bf(h1b) << 16) |
                     (unsigned)(unsigned short)f2bf(h1a);
      unsigned* dst = (unsigned*)(h1g + (p & 1) * BB * HH +
                                  (bt * 16 + r1) * HH + ht * 16 + c1);
      __hip_atomic_store(dst, val, __ATOMIC_RELAXED, __HIP_MEMORY_SCOPE_AGENT);
    }
    if (tid >= 256 && p > 0) {
      float rA = fast_sigmoid(gt[0][3][r2][c2] + gt[1][3][r2][c2]);
      float zA = fast_sigmoid(gt[0][4][r2][c2] + gt[1][4][r2][c2]);
      float nA = fast_tanh(gt[0][5][r2][c2] + rA * gt[1][5][r2][c2]);
      h2a = nA + zA * (h2a - nA);
      float rB = fast_sigmoid(gt[0][3][r2][c2 + 1] + gt[1][3][r2][c2 + 1]);
      float zB = fast_sigmoid(gt[0][4][r2][c2 + 1] + gt[1][4][r2][c2 + 1]);
      float nB = fast_tanh(gt[0][5][r2][c2 + 1] + rB * gt[1][5][r2][c2 + 1]);
      h2b = nB + zB * (h2b - nB);
      unsigned val = ((unsigned)(unsigned short)f2bf(h2b) << 16) |
                     (unsigned)(unsigned short)f2bf(h2a);
      unsigned* dst = (unsigned*)(h2g + ((p + 1) & 1) * BB * HH +
                                  (bt * 16 + r2) * HH + ht * 16 + c2);
      __hip_atomic_store(dst, val, __ATOMIC_RELAXED, __HIP_MEMORY_SCOPE_AGENT);
    }
    __syncthreads();  // vmcnt(0) drain: all sc1 publishes globally visible
    if (tid == 0) st_flag(fl + ht, (unsigned)(p + 1));  // plain store, no RMW
  }

  // ---- FC epilogue: out = h2[511] @ Wfc^T + bfc ----
  if (tid < 64) {
    const unsigned tgt = (unsigned)(TT + 1);
    int guard = 0;
    for (;;) {
      unsigned v = tgt;
      if (lane < 16) v = ld_flag(fl + lane);
      if (__all(v >= tgt) || ++guard > (1 << 20)) break;
    }
  }
  __syncthreads();
  {
    const u64* s1 = (const u64*)(h2g + 1 * BB * HH + tbase);  // parity (TT+1)&1=1
    u64 t1[4];
    if (tid < 256) {
#pragma unroll
      for (int qq = 0; qq < 4; ++qq) t1[qq] = ld_sc1(s1 + tid * 4 + qq);
    }
    u64* d1 = (u64*)&ldsA[0][0][0];
    if (tid < 256) {
#pragma unroll
      for (int qq = 0; qq < 4; ++qq) {
        int i = tid * 4 + qq, row = i >> 6, c = i & 63;
        d1[row * (LDH / 4) + c] = t1[qq];
      }
    }
  }
  __syncthreads();
  if (w == 0) {
    float bbv = bfc[j];
    floatx4 acc = floatx4{bbv, bbv, bbv, bbv};
#pragma unroll
    for (int f = 0; f < 8; ++f) {
      short8 a = *(const short8*)(&ldsA[0][col][0] + f * 32 + quad * 8);
      short8 bfrag = cvt8(Wfc + j * HH + f * 32 + quad * 8);
      acc = __builtin_amdgcn_mfma_f32_16x16x32_bf16(a, bfrag, acc, 0, 0, 0);
    }
#pragma unroll
    for (int i = 0; i < 4; ++i)
      out[(size_t)(bt * 16 + quad * 4 + i) * HH + j] = acc[i];
  }
}

extern "C" void kernel_launch(void* const* d_in, const int* in_sizes, int n_in,
                              void* d_out, int out_size, void* d_ws,
                              size_t ws_size, hipStream_t stream) {
  const float* x = (const float*)d_in[0];
  const float* Wih0 = (const float*)d_in[1];
  const float* Whh0 = (const float*)d_in[2];
  const float* bih0 = (const float*)d_in[3];
  const float* bhh0 = (const float*)d_in[4];
  const float* Wih1 = (const float*)d_in[5];
  const float* Whh1 = (const float*)d_in[6];
  const float* bih1 = (const float*)d_in[7];
  const float* bhh1 = (const float*)d_in[8];
  const float* Wfc = (const float*)d_in[9];
  const float* bfc = (const float*)d_in[10];

  short* wb = (short*)d_ws;
  short* h1g = wb + H1G_OFF;
  short* h2g = wb + H2G_OFF;
  unsigned* flags = (unsigned*)((char*)d_ws + FLAGS_OFF_BYTES);
  unsigned* hz = (unsigned*)(wb + H1G_OFF);

  cvt_weights<<<(W_TOTAL + 255) / 256, 256, 0, stream>>>(Wih0, Whh0, Wih1, Whh1, wb);
  init_state<<<(2 * BB * HH + 255) / 256, 256, 0, stream>>>(hz, flags);
  gru_sync<<<256, 384, 0, stream>>>(x, wb, bih0, bhh0, bih1, bhh1, Wfc, bfc,
                                    h1g, h2g, flags, (float*)d_out);
}